// Round 10
// baseline (150.093 us; speedup 1.0000x reference)
//
#include <hip/hip_runtime.h>
#include <stdint.h>

#define NN 4096
#define MM 8192
#define DD 512

typedef __bf16 bf16x8 __attribute__((ext_vector_type(8)));
typedef float f32x4 __attribute__((ext_vector_type(4)));
typedef float f32x16 __attribute__((ext_vector_type(16)));

// VALU-pipe partial reduction (R7-verified correct): x += rot16(x, k).
template <int CTRL>
__device__ __forceinline__ float dpp_radd(float x) {
  int xi = __float_as_int(x);
  int mv = __builtin_amdgcn_update_dpp(xi, xi, CTRL, 0xF, 0xF, false);
  return x + __int_as_float(mv);
}
__device__ __forceinline__ float swz_add_xor16(float x) {
  int sv = __builtin_amdgcn_ds_swizzle(__float_as_int(x), 0x401F);
  return x + __int_as_float(sv);
}

// One wave per row. Lane l holds row elements [8l, 8l+8) (coalesced f32x4 x2).
// BOTH X and SV are written in MFMA-fragment order (R9-verified transform):
//   F[((r>>5)*32 + (l>>1))*64 + (l&1)*32 + (r&31)] = row r, elems [8l, 8l+8)
// so the GEMM reads every A/B fragment with ONE coalesced 16B/lane global
// load (lane = h*32 + r31 mapping == the 32x32x16 operand layout used —
// and numerically verified — by the R4..R9 LDS path).
// Also: exact fp32 row-norms and out[]=IC init.
__global__ __launch_bounds__(256) void convert_norm_kernel(
    const float* __restrict__ X, const float* __restrict__ SV,
    bf16x8* __restrict__ Xf, bf16x8* __restrict__ SVf,
    float* __restrict__ x2, float* __restrict__ sv2,
    float* __restrict__ out, const float* __restrict__ IC) {
  int wid = blockIdx.x * 4 + (threadIdx.x >> 6);
  int lane = threadIdx.x & 63;
  const float* src;
  float* nrm;
  bf16x8* dstF;
  bool isX = (wid < NN);
  int r = isX ? wid : wid - NN;
  if (isX) {
    src = X + (size_t)r * DD;
    nrm = x2 + r;
    dstF = Xf;
    if (lane == 0) out[r] = IC[0];
  } else {
    src = SV + (size_t)r * DD;
    nrm = sv2 + r;
    dstF = SVf;
  }
  const f32x4* s = (const f32x4*)src;
  f32x4 a = s[2 * lane];      // elements 8l .. 8l+3
  f32x4 b = s[2 * lane + 1];  // elements 8l+4 .. 8l+7
  float sum = a.x * a.x + a.y * a.y + a.z * a.z + a.w * a.w +
              b.x * b.x + b.y * b.y + b.z * b.z + b.w * b.w;
  bf16x8 o;
  o[0] = (__bf16)a.x; o[1] = (__bf16)a.y; o[2] = (__bf16)a.z; o[3] = (__bf16)a.w;
  o[4] = (__bf16)b.x; o[5] = (__bf16)b.y; o[6] = (__bf16)b.z; o[7] = (__bf16)b.w;
  dstF[((size_t)((r >> 5) * 32 + (lane >> 1))) * 64 + (lane & 1) * 32 + (r & 31)] = o;
#pragma unroll
  for (int m = 32; m >= 1; m >>= 1) sum += __shfl_xor(sum, m, 64);
  if (lane == 0) *nrm = sum;
}

// BARRIER-FREE GEMM: no LDS, no __syncthreads in the K-loop. Both operands
// come straight from global memory in fragment order (one coalesced
// global_load_dwordx4 per fragment). With no s_barrier there is no forced
// vmcnt(0) drain — the compiler emits fine-grained vmcnt(N) and pipelines
// loads against MFMAs (the AITER/hipBLASLt pattern the barriered K-loops
// of R4..R9 could not express; their 8 drains pinned MfmaUtil at ~20%).
// 128x128 tile, 4 waves (2x2), each wave 64x64 via 2x2 mfma_f32_32x32x16.
// Wave pairs {0,1}/{2,3} share A lines, {0,2}/{1,3} share B lines -> L1 reuse.
__global__ __launch_bounds__(256, 3) void rbf_gemm_kernel(
    const bf16x8* __restrict__ Xf, const bf16x8* __restrict__ SVf,
    const float* __restrict__ x2, const float* __restrict__ sv2,
    const float* __restrict__ DC, const float* __restrict__ gamma_p,
    float* __restrict__ out) {
  const int t = threadIdx.x;
  const int lane = t & 63;
  const int wave = t >> 6;
  const int n0 = blockIdx.x * 128;
  const int m0 = blockIdx.y * 128;

  const int wave_m = wave & 1;   // m-dir of C
  const int wave_n = wave >> 1;  // n-dir of C
  const int l31 = lane & 31;
  const int lhi = lane >> 5;

  // fragment pointers: row-group rg covers 32 rows; 32 k-slices (sg) of 16.
  // chunk index = rg*2048 + sg*64 + lane.
  const int rgA = blockIdx.x * 4 + wave_n * 2;
  const int rgB = blockIdx.y * 4 + wave_m * 2;
  const bf16x8* ap0 = Xf + (size_t)rgA * 2048 + lane;
  const bf16x8* ap1 = ap0 + 2048;
  const bf16x8* bp0 = SVf + (size_t)rgB * 2048 + lane;
  const bf16x8* bp1 = bp0 + 2048;

  f32x16 acc[2][2];
#pragma unroll
  for (int i = 0; i < 2; ++i)
#pragma unroll
    for (int j = 0; j < 2; ++j)
#pragma unroll
      for (int r = 0; r < 16; ++r) acc[i][j][r] = 0.0f;

  // explicit 2-stage software pipeline; compiler deepens it as regs allow
  bf16x8 a0 = ap0[0], a1 = ap1[0], b0 = bp0[0], b1 = bp1[0];
#pragma unroll
  for (int sg = 0; sg < 32; ++sg) {
    bf16x8 na0, na1, nb0, nb1;
    if (sg + 1 < 32) {
      const size_t o = (size_t)(sg + 1) * 64;
      na0 = ap0[o];
      na1 = ap1[o];
      nb0 = bp0[o];
      nb1 = bp1[o];
    }
    acc[0][0] = __builtin_amdgcn_mfma_f32_32x32x16_bf16(a0, b0, acc[0][0], 0, 0, 0);
    acc[0][1] = __builtin_amdgcn_mfma_f32_32x32x16_bf16(a0, b1, acc[0][1], 0, 0, 0);
    acc[1][0] = __builtin_amdgcn_mfma_f32_32x32x16_bf16(a1, b0, acc[1][0], 0, 0, 0);
    acc[1][1] = __builtin_amdgcn_mfma_f32_32x32x16_bf16(a1, b1, acc[1][1], 0, 0, 0);
    a0 = na0; a1 = na1; b0 = nb0; b1 = nb1;
  }

  // ---- epilogue ----
  const float g = gamma_p[0];
  const float c2 = g * 1.4426950408889634f;  // gamma * log2(e)

  float sv2v[2], dcv[2];
  const int colb = m0 + wave_m * 64 + l31;
  sv2v[0] = sv2[colb];
  dcv[0] = DC[colb];
  sv2v[1] = sv2[colb + 32];
  dcv[1] = DC[colb + 32];

#pragma unroll
  for (int i = 0; i < 2; ++i) {
    // C row = rowb + 8*g4 + r2, where reg = g4*4 + r2
    const int rowb = n0 + wave_n * 64 + i * 32 + 4 * lhi;
    float val[16];
#pragma unroll
    for (int g4 = 0; g4 < 4; ++g4) {
      f32x4 xv = *(const f32x4*)(x2 + rowb + 8 * g4);
#pragma unroll
      for (int r2 = 0; r2 < 4; ++r2) {
        const int reg = g4 * 4 + r2;
        float v = 0.0f;
#pragma unroll
        for (int j = 0; j < 2; ++j) {
          float d2 = xv[r2] + sv2v[j] - 2.0f * acc[i][j][reg];
          d2 = fmaxf(d2, 0.0f);
          v += exp2f(-c2 * d2) * dcv[j];
        }
        val[reg] = v;
      }
    }
    // reduce over 32 column-lanes: 4 DPP row-rotations (VALU) + ds_swizzle xor16
#pragma unroll
    for (int reg = 0; reg < 16; ++reg) {
      float v = val[reg];
      v = dpp_radd<0x121>(v);  // row_ror:1
      v = dpp_radd<0x122>(v);  // row_ror:2
      v = dpp_radd<0x124>(v);  // row_ror:4
      v = dpp_radd<0x128>(v);  // row_ror:8
      val[reg] = swz_add_xor16(v);
    }
    if (l31 == 0) {
#pragma unroll
      for (int g4 = 0; g4 < 4; ++g4)
#pragma unroll
        for (int r2 = 0; r2 < 4; ++r2)
          atomicAdd(&out[rowb + 8 * g4 + r2], val[g4 * 4 + r2]);
    }
  }
}

extern "C" void kernel_launch(void* const* d_in, const int* in_sizes, int n_in,
                              void* d_out, int out_size, void* d_ws, size_t ws_size,
                              hipStream_t stream) {
  const float* X = (const float*)d_in[0];
  const float* SV = (const float*)d_in[1];
  const float* DC = (const float*)d_in[2];
  const float* IC = (const float*)d_in[3];
  const float* gamma = (const float*)d_in[4];
  float* out = (float*)d_out;

  char* ws = (char*)d_ws;
  bf16x8* Xf = (bf16x8*)ws;                                   // 4 MB (frag order)
  bf16x8* SVf = (bf16x8*)(ws + (size_t)NN * DD * 2);          // 8 MB (frag order)
  float* x2 = (float*)(ws + (size_t)(NN + MM) * DD * 2);      // 16 KB
  float* sv2 = x2 + NN;                                       // 32 KB

  convert_norm_kernel<<<(NN + MM) / 4, 256, 0, stream>>>(X, SV, Xf, SVf, x2, sv2, out, IC);
  dim3 grid(NN / 128, MM / 128);
  rbf_gemm_kernel<<<grid, 256, 0, stream>>>(Xf, SVf, x2, sv2, DC, gamma, out);
}